// Round 7
// baseline (1689.237 us; speedup 1.0000x reference)
//
#include <hip/hip_runtime.h>
#include <cstdint>
#include <cstddef>

typedef __bf16 bf16;
typedef __attribute__((ext_vector_type(8))) __bf16 bf16x8;
typedef __attribute__((ext_vector_type(4))) __bf16 bf16x4;
typedef __attribute__((ext_vector_type(4))) float f32x4;

#define ADIM 1024
#define ASEQ 2048
#define ABATCH 8

__device__ __forceinline__ void gload_lds16(const void* g, void* l) {
  __builtin_amdgcn_global_load_lds(
      (const __attribute__((address_space(1))) void*)g,
      (__attribute__((address_space(3))) void*)l,
      16, 0, 0);
}

__device__ __forceinline__ f32x4 mfma16(bf16x8 a, bf16x8 b, f32x4 c) {
  return __builtin_amdgcn_mfma_f32_16x16x32_bf16(a, b, c, 0, 0, 0);
}

// ---------------- cast x (fp32 -> bf16), vectorized ----------------
__global__ void k_cast_x(const float* __restrict__ x, bf16* __restrict__ xb, int n4) {
  int i = blockIdx.x * blockDim.x + threadIdx.x;
  int stride = gridDim.x * blockDim.x;
  for (; i < n4; i += stride) {
    float4 f = ((const float4*)x)[i];
    bf16x4 o = { (bf16)f.x, (bf16)f.y, (bf16)f.z, (bf16)f.w };
    ((bf16x4*)xb)[i] = o;
  }
}

// ------- weights: LDS-tiled transpose + cast (coalesced both sides) -------
__global__ __launch_bounds__(256) void k_prep_w_t(
    const float* __restrict__ Wq, const float* __restrict__ Wk,
    const float* __restrict__ Wv, const float* __restrict__ Wo,
    bf16* __restrict__ WcT, bf16* __restrict__ WoT) {
  const int b = blockIdx.x;
  const int which = b >> 8, t = b & 255;
  const int n0 = (t & 15) * 64, k0 = (t >> 4) * 64;
  const float* W = (which == 0) ? Wq : (which == 1) ? Wk : (which == 2) ? Wv : Wo;
  bf16* out = (which < 3) ? (WcT + (size_t)which * ADIM * ADIM) : WoT;

  __shared__ float tile[64][69];
  const int r = threadIdx.x >> 4, c4 = (threadIdx.x & 15) * 4;
#pragma unroll
  for (int p = 0; p < 4; ++p) {
    float4 f = *(const float4*)&W[(size_t)(k0 + p * 16 + r) * ADIM + n0 + c4];
    tile[p * 16 + r][c4 + 0] = f.x;
    tile[p * 16 + r][c4 + 1] = f.y;
    tile[p * 16 + r][c4 + 2] = f.z;
    tile[p * 16 + r][c4 + 3] = f.w;
  }
  __syncthreads();
#pragma unroll
  for (int p = 0; p < 4; ++p) {
    const int nn = p * 16 + r;
    bf16x4 o;
#pragma unroll
    for (int j = 0; j < 4; ++j) o[j] = (bf16)tile[c4 + j][nn];
    *(bf16x4*)&out[(size_t)(n0 + nn) * ADIM + k0 + c4] = o;
  }
}

// ====== 256x256-tile BK=32 GEMM, A:3-slot / B:2-slot ring, 80 KiB LDS ======
// -> 2 blocks/CU (160 KiB) so independent blocks overlap LDS and MFMA phases.
// C[m][n] = sum_k A[m][k]*BT[n][k]; 512 threads = 8 waves (2M x 4N),
// per-wave output 128x64 (acc[8][4]).
// Per step t: read sA[t%3], sB[t&1]; stage B(t+1) (2 gloads, 1-ahead: B is
// L2-hot weights, ~200cy) then A(t+2) (2 gloads, 2-ahead: A streams HBM).
// End-of-step: vmcnt(2) + s_barrier. In-order retirement: outstanding queue
// = [A(t+1)x2, B(t+1)x2, A(t+2)x2]; vmcnt(2) retires A(t+1),B(t+1),
// leaves A(t+2) in flight. Never drains mid-loop.
// WAR: stage targets were last read 1 (B) / 1 (A, slot (t+2)%3=(t-1)%3) step
// ago; those ds_reads complete before their MFMAs which precede that step's
// end barrier; overwriting gloads are issued after it.
// LDS row = 32 bf16 = 4 x 16B slots; slot (r,s) holds global (r, s^((r>>1)&3))
// (involution; inverse applied on per-lane GLOBAL source, linear gload dest).
// MODE 0: fused QKV epilogue (256 | 1024 so block n-range uniform);
// MODE 1: fp32 out + bias.
template<int MODE>
__global__ __launch_bounds__(512, 4) void k_gemm2x(
    const bf16* __restrict__ A, const bf16* __restrict__ BT,
    const float* __restrict__ bias0, const float* __restrict__ bias1,
    const float* __restrict__ bias2,
    bf16* __restrict__ Qo, bf16* __restrict__ Ko, bf16* __restrict__ Vto,
    float* __restrict__ outF, int ntn)
{
  constexpr int K = 1024;
  constexpr int KT = K / 32;   // 32 steps of BK=32
  const int nwg = gridDim.x;
  const int cpx = nwg >> 3;
  const int flat = blockIdx.x;
  const int sw = (flat & 7) * cpx + (flat >> 3);   // grid % 8 == 0 (bijective)
  const int bx = sw % ntn, by = sw / ntn;
  const int m0 = by * 256, n0 = bx * 256;

  const int tid = threadIdx.x;
  const int l = tid & 63, w = tid >> 6;
  const int wm = w >> 2, wn = w & 3;     // 2M x 4N
  const int lr = l & 15, kg = l >> 4;    // kg in 0..3 (col16 within BK=32)

  __shared__ alignas(16) bf16 sA[3][256 * 32];   // 48 KiB
  __shared__ alignas(16) bf16 sB[2][256 * 32];   // 32 KiB  -> 80 KiB total

  f32x4 acc[8][4] = {};

  // swizzled ds_read byte offsets: global col16=kg of row r
  int oA[8], oB[4];
#pragma unroll
  for (int i = 0; i < 8; ++i) {
    int r = wm * 128 + i * 16 + lr;
    oA[i] = (r * 4 + (kg ^ ((r >> 1) & 3))) * 16;
  }
#pragma unroll
  for (int j = 0; j < 4; ++j) {
    int r = wn * 64 + j * 16 + lr;
    oB[j] = (r * 4 + (kg ^ ((r >> 1) & 3))) * 16;
  }

  auto stageA = [&](int sp, int kt, int half) {
    int u = half * 512 + tid;
    int prow = u >> 2, ps = u & 3;
    int lc = ps ^ ((prow >> 1) & 3);              // inverse swizzle on source
    gload_lds16(A + (size_t)(m0 + prow) * K + kt * 32 + lc * 8,
                &sA[sp][(half * 512 + w * 64) * 8]);
  };
  auto stageB = [&](int sp, int kt, int half) {
    int u = half * 512 + tid;
    int prow = u >> 2, ps = u & 3;
    int lc = ps ^ ((prow >> 1) & 3);
    gload_lds16(BT + (size_t)(n0 + prow) * K + kt * 32 + lc * 8,
                &sB[sp][(half * 512 + w * 64) * 8]);
  };

  // prologue: A0->slot0, B0->slot0, A1->slot1; vmcnt(2) leaves A1 in flight
  stageA(0, 0, 0); stageA(0, 0, 1);
  stageB(0, 0, 0); stageB(0, 0, 1);
  stageA(1, 1, 0); stageA(1, 1, 1);
  asm volatile("s_waitcnt vmcnt(2)\n\ts_barrier" ::: "memory");

  for (int t = 0; t < KT; ++t) {
    const int sa = t % 3, sb = t & 1;
    const char* bA = (const char*)&sA[sa][0];
    const char* bB = (const char*)&sB[sb][0];

    bf16x8 af[8], bfr[4];
#pragma unroll
    for (int i = 0; i < 8; ++i) af[i] = *(const bf16x8*)(bA + oA[i]);
#pragma unroll
    for (int j = 0; j < 4; ++j) bfr[j] = *(const bf16x8*)(bB + oB[j]);

    // stage B(t+1) first, A(t+2) second (issue order = ledger order)
    const int tb = (t + 1 < KT) ? t + 1 : t;     // dummy tail keeps ledger uniform
    const int ta = (t + 2 < KT) ? t + 2 : t;
    stageB((t + 1) & 1, tb, 0); stageB((t + 1) & 1, tb, 1);
    stageA((t + 2) % 3, ta, 0); stageA((t + 2) % 3, ta, 1);

    __builtin_amdgcn_s_setprio(1);
#pragma unroll
    for (int i = 0; i < 8; ++i)
#pragma unroll
      for (int j = 0; j < 4; ++j)
        acc[i][j] = mfma16(af[i], bfr[j], acc[i][j]);
    __builtin_amdgcn_s_setprio(0);

    asm volatile("s_waitcnt vmcnt(2)\n\ts_barrier" ::: "memory");
  }
  asm volatile("s_waitcnt vmcnt(0)" ::: "memory");     // drain tail dummies

  // ---- epilogue ----
  const int cb = n0 >> 10;          // uniform per block (256 | 1024)
#pragma unroll
  for (int i = 0; i < 8; ++i) {
#pragma unroll
    for (int jj = 0; jj < 4; ++jj) {
      const int n = n0 + wn * 64 + jj * 16 + lr;
      const int m0r = m0 + wm * 128 + i * 16 + kg * 4;
      if (MODE == 0) {
        const int nn = n & 1023;
        if (cb == 0) {
          const float b_ = bias0[nn];
#pragma unroll
          for (int r = 0; r < 4; ++r)
            Qo[(size_t)(m0r + r) * ADIM + nn] = (bf16)(acc[i][jj][r] + b_);
        } else if (cb == 1) {
          const float b_ = bias1[nn];
#pragma unroll
          for (int r = 0; r < 4; ++r) {
            float v = acc[i][jj][r] + b_;
            Ko[(size_t)(m0r + r) * ADIM + nn] = (bf16)(v > 0.f ? v + 1.f : __expf(v));
          }
        } else {
          const float b_ = bias2[nn];
          const int bb = m0r >> 11, t0c = m0r & 2047;
          bf16x4 pk;
#pragma unroll
          for (int r = 0; r < 4; ++r) pk[r] = (bf16)(acc[i][jj][r] + b_);
          *(bf16x4*)&Vto[((size_t)bb * ADIM + nn) * ASEQ + t0c] = pk;
        }
      } else {
        const float b_ = bias0[n];
#pragma unroll
        for (int r = 0; r < 4; ++r)
          outF[(size_t)(m0r + r) * ADIM + n] = acc[i][jj][r] + b_;
      }
    }
  }
}

// --------- windowed decay attention: one (batch, 64-row q-tile) per WG ---------
__global__ __launch_bounds__(256) void k_attn(
    const bf16* __restrict__ Qg, const bf16* __restrict__ Kg,
    const bf16* __restrict__ Vt, bf16* __restrict__ Rb,
    const float* __restrict__ decay_param)
{
  const int b = blockIdx.y;
  const int T0 = blockIdx.x * 64;
  const int tid = threadIdx.x;
  const int l = tid & 63, w = tid >> 6;
  const int lr = l & 15, lk = (l >> 4) * 8;

  const float dp = decay_param[0];
  const float decay = 1.f / (1.f + __expf(-dp));
  const float l2d = __log2f(decay);

  __shared__ alignas(16) bf16 lQ[2][64 * 32];
  __shared__ alignas(16) bf16 lK[2][128 * 32];
  __shared__ alignas(16) bf16 lV[2][128 * 32];
  __shared__ alignas(16) bf16 lP[64 * 136];

  const bf16* Qb = Qg + (size_t)(b * ASEQ + T0) * ADIM;

  auto stageQK = [&](int buf, int k0) {
    {
      const bf16* g = Qb + (size_t)(w * 16 + (l >> 2)) * ADIM + k0 + (l & 3) * 8;
      gload_lds16(g, &lQ[buf][w * 16 * 32]);
    }
#pragma unroll
    for (int cc = 0; cc < 2; ++cc) {
      int c = 2 * w + cc;
      int sg = T0 - 64 + c * 16 + (l >> 2);
      if (sg < 0) sg = 0;
      const bf16* g = Kg + (size_t)(b * ASEQ + sg) * ADIM + k0 + (l & 3) * 8;
      gload_lds16(g, &lK[buf][c * 16 * 32]);
    }
  };

  f32x4 sc[4][2] = {};
  stageQK(0, 0);
  __syncthreads();
  for (int kt = 0; kt < 32; ++kt) {
    int cur = kt & 1;
    if (kt + 1 < 32) stageQK(cur ^ 1, (kt + 1) * 32);
    bf16x8 af[4], bfr[2];
#pragma unroll
    for (int i = 0; i < 4; ++i)
      af[i] = *(const bf16x8*)&lQ[cur][(i * 16 + lr) * 32 + lk];
#pragma unroll
    for (int j = 0; j < 2; ++j)
      bfr[j] = *(const bf16x8*)&lK[cur][(w * 32 + j * 16 + lr) * 32 + lk];
#pragma unroll
    for (int i = 0; i < 4; ++i)
#pragma unroll
      for (int j = 0; j < 2; ++j)
        sc[i][j] = mfma16(af[i], bfr[j], sc[i][j]);
    __syncthreads();
  }

  const int er = (l >> 4) * 4, ec = l & 15;
#pragma unroll
  for (int i = 0; i < 4; ++i)
#pragma unroll
    for (int j = 0; j < 2; ++j)
#pragma unroll
      for (int r = 0; r < 4; ++r) {
        int tl = i * 16 + er + r;
        int sl = w * 32 + j * 16 + ec;
        int sg = T0 - 64 + sl;
        int delta = (T0 + tl) - 1 - sg;
        float wgt = (delta >= 0 && delta < 64 && sg >= 0)
                        ? exp2f((float)delta * l2d) : 0.f;
        lP[tl * 136 + sl] = (bf16)(sc[i][j][r] * wgt);
      }

  auto stageV = [&](int buf, int g) {
    int nc = g >> 2, ks = g & 3;
#pragma unroll
    for (int cc = 0; cc < 2; ++cc) {
      int c = 2 * w + cc;
      int drow = nc * 128 + c * 16 + (l >> 2);
      int scol = T0 - 64 + ks * 32 + (l & 3) * 8;
      if (scol < 0) scol = 0;
      const bf16* gv = Vt + ((size_t)b * ADIM + drow) * ASEQ + scol;
      gload_lds16(gv, &lV[buf][c * 16 * 32]);
    }
  };

  f32x4 o[4][2] = {};
  stageV(0, 0);
  __syncthreads();

  for (int g = 0; g < 32; ++g) {
    int cur = g & 1;
    if (g + 1 < 32) stageV(cur ^ 1, g + 1);
    int nc = g >> 2, ks = g & 3;
    bf16x8 af[4], bfr[2];
#pragma unroll
    for (int i = 0; i < 4; ++i)
      af[i] = *(const bf16x8*)&lP[(i * 16 + lr) * 136 + ks * 32 + lk];
#pragma unroll
    for (int j = 0; j < 2; ++j)
      bfr[j] = *(const bf16x8*)&lV[cur][(w * 32 + j * 16 + lr) * 32 + lk];
#pragma unroll
    for (int i = 0; i < 4; ++i)
#pragma unroll
      for (int j = 0; j < 2; ++j)
        o[i][j] = mfma16(af[i], bfr[j], o[i][j]);
    if (ks == 3) {
#pragma unroll
      for (int i = 0; i < 4; ++i)
#pragma unroll
        for (int j = 0; j < 2; ++j) {
#pragma unroll
          for (int r = 0; r < 4; ++r) {
            int tl = i * 16 + er + r;
            int dl = nc * 128 + w * 32 + j * 16 + ec;
            Rb[(size_t)(b * ASEQ + T0 + tl) * ADIM + dl] = (bf16)o[i][j][r];
          }
#pragma unroll
          for (int r = 0; r < 4; ++r) o[i][j][r] = 0.f;
        }
    }
    __syncthreads();
  }
}

extern "C" void kernel_launch(void* const* d_in, const int* in_sizes, int n_in,
                              void* d_out, int out_size, void* d_ws, size_t ws_size,
                              hipStream_t stream) {
  const float* x  = (const float*)d_in[0];
  const float* Wq = (const float*)d_in[1];
  const float* bq = (const float*)d_in[2];
  const float* Wk = (const float*)d_in[3];
  const float* bk = (const float*)d_in[4];
  const float* Wv = (const float*)d_in[5];
  const float* bv = (const float*)d_in[6];
  const float* Wo = (const float*)d_in[7];
  const float* bo = (const float*)d_in[8];
  const float* dp = (const float*)d_in[9];
  float* out = (float*)d_out;

  char* ws = (char*)d_ws;
  bf16* Xb  = (bf16*)(ws + ((size_t)0 << 20));    // [16384][1024]
  bf16* Qb  = (bf16*)(ws + ((size_t)32 << 20));
  bf16* Kb  = (bf16*)(ws + ((size_t)64 << 20));
  bf16* Vtb = (bf16*)(ws + ((size_t)96 << 20));   // [8][1024][2048]
  bf16* Rbb = (bf16*)(ws + ((size_t)128 << 20));
  bf16* WcT = (bf16*)(ws + ((size_t)160 << 20));  // [3072][1024]
  bf16* WoT = (bf16*)(ws + ((size_t)166 << 20));  // [1024][1024]

  const int M = ABATCH * ASEQ;  // 16384

  k_cast_x<<<2048, 256, 0, stream>>>(x, Xb, (M * ADIM) / 4);
  k_prep_w_t<<<1024, 256, 0, stream>>>(Wq, Wk, Wv, Wo, WcT, WoT);
  k_gemm2x<0><<<768, 512, 0, stream>>>(
      Xb, WcT, bq, bk, bv, Qb, Kb, Vtb, nullptr, 12);
  k_attn<<<dim3(32, 8), 256, 0, stream>>>(Qb, Kb, Vtb, Rbb, dp);
  k_gemm2x<1><<<256, 512, 0, stream>>>(
      Rbb, WoT, bo, nullptr, nullptr, nullptr, nullptr, nullptr, out, 4);
}

// Round 8
// 211.691 us; speedup vs baseline: 7.9797x; 7.9797x over previous
//
#include <hip/hip_runtime.h>
#include <cstdint>
#include <cstddef>

typedef __bf16 bf16;
typedef __attribute__((ext_vector_type(8))) __bf16 bf16x8;
typedef __attribute__((ext_vector_type(4))) __bf16 bf16x4;
typedef __attribute__((ext_vector_type(4))) float f32x4;

#define ADIM 1024
#define ASEQ 2048
#define ABATCH 8

__device__ __forceinline__ void gload_lds16(const void* g, void* l) {
  __builtin_amdgcn_global_load_lds(
      (const __attribute__((address_space(1))) void*)g,
      (__attribute__((address_space(3))) void*)l,
      16, 0, 0);
}

__device__ __forceinline__ f32x4 mfma16(bf16x8 a, bf16x8 b, f32x4 c) {
  return __builtin_amdgcn_mfma_f32_16x16x32_bf16(a, b, c, 0, 0, 0);
}

// ---------------- cast x (fp32 -> bf16), vectorized ----------------
__global__ void k_cast_x(const float* __restrict__ x, bf16* __restrict__ xb, int n4) {
  int i = blockIdx.x * blockDim.x + threadIdx.x;
  int stride = gridDim.x * blockDim.x;
  for (; i < n4; i += stride) {
    float4 f = ((const float4*)x)[i];
    bf16x4 o = { (bf16)f.x, (bf16)f.y, (bf16)f.z, (bf16)f.w };
    ((bf16x4*)xb)[i] = o;
  }
}

// ------- weights: LDS-tiled transpose + cast (coalesced both sides) -------
__global__ __launch_bounds__(256) void k_prep_w_t(
    const float* __restrict__ Wq, const float* __restrict__ Wk,
    const float* __restrict__ Wv, const float* __restrict__ Wo,
    bf16* __restrict__ WcT, bf16* __restrict__ WoT) {
  const int b = blockIdx.x;
  const int which = b >> 8, t = b & 255;
  const int n0 = (t & 15) * 64, k0 = (t >> 4) * 64;
  const float* W = (which == 0) ? Wq : (which == 1) ? Wk : (which == 2) ? Wv : Wo;
  bf16* out = (which < 3) ? (WcT + (size_t)which * ADIM * ADIM) : WoT;

  __shared__ float tile[64][69];
  const int r = threadIdx.x >> 4, c4 = (threadIdx.x & 15) * 4;
#pragma unroll
  for (int p = 0; p < 4; ++p) {
    float4 f = *(const float4*)&W[(size_t)(k0 + p * 16 + r) * ADIM + n0 + c4];
    tile[p * 16 + r][c4 + 0] = f.x;
    tile[p * 16 + r][c4 + 1] = f.y;
    tile[p * 16 + r][c4 + 2] = f.z;
    tile[p * 16 + r][c4 + 3] = f.w;
  }
  __syncthreads();
#pragma unroll
  for (int p = 0; p < 4; ++p) {
    const int nn = p * 16 + r;
    bf16x4 o;
#pragma unroll
    for (int j = 0; j < 4; ++j) o[j] = (bf16)tile[c4 + j][nn];
    *(bf16x4*)&out[(size_t)(n0 + nn) * ADIM + k0 + c4] = o;
  }
}

// ====== 256x256-tile BK=64 GEMM, double-buffered, 16 steps, 1 fence/step =====
// C[m][n] = sum_k A[m][k]*BT[n][k]; 512 threads = 8 waves (2M x 4N),
// per-wave output 128x64 (acc[8][4] in AGPR). LDS 128 KiB (1 block/CU).
// Step t (buf c=t&1): phase0 {12 ds_read (k 0..31) | issue all 8 gloads of
// tile t+1 into buf c^1 | 32 MFMA}; phase1 {12 ds_read (k 32..63) | 32 MFMA};
// then vmcnt(0)+s_barrier. Drain is cheap: the 8 loads were issued ~2500 cyc
// earlier (issue-early/wait-late), not stage-then-wait.
// WAR: buf c^1 was last read in step t-1; those ds_reads complete before
// their MFMAs, which precede the step-(t-1) fence; overwrites issue after it.
// LDS row = 64 bf16 = 8 x 16B slots; slot (r,s) holds global (r, s^(r&7))
// (involution; inverse applied on per-lane GLOBAL source, linear gload dest).
// Readers (16-lane col-slice, rows r..r+15): slots g^(r&7) cover all 8
// columns twice -> 2 lanes/bank = free. kh=1 slot = kh0 slot ^4 -> byte ^64.
// MODE 0: fused QKV epilogue (256 | 1024 so block n-range uniform);
// MODE 1: fp32 out + bias.
template<int MODE>
__global__ __launch_bounds__(512, 2) void k_gemm64(
    const bf16* __restrict__ A, const bf16* __restrict__ BT,
    const float* __restrict__ bias0, const float* __restrict__ bias1,
    const float* __restrict__ bias2,
    bf16* __restrict__ Qo, bf16* __restrict__ Ko, bf16* __restrict__ Vto,
    float* __restrict__ outF, int ntn)
{
  constexpr int K = 1024;
  constexpr int KT = K / 64;   // 16 steps of BK=64
  const int nwg = gridDim.x;
  const int cpx = nwg >> 3;
  const int flat = blockIdx.x;
  const int sw = (flat & 7) * cpx + (flat >> 3);   // grid % 8 == 0 (bijective)
  const int bx = sw % ntn, by = sw / ntn;
  const int m0 = by * 256, n0 = bx * 256;

  const int tid = threadIdx.x;
  const int l = tid & 63, w = tid >> 6;
  const int wm = w >> 2, wn = w & 3;     // 2M x 4N
  const int lr = l & 15, kg = l >> 4;    // kg in 0..3

  __shared__ alignas(16) bf16 sA[2][256 * 64];   // 64 KiB
  __shared__ alignas(16) bf16 sB[2][256 * 64];   // 64 KiB

  f32x4 acc[8][4] = {};

  // swizzled ds_read byte offsets for kh=0 (kh=1: offset ^ 64)
  int oA[8], oB[4];
#pragma unroll
  for (int i = 0; i < 8; ++i) {
    int r = wm * 128 + i * 16 + lr;
    oA[i] = (r * 8 + (kg ^ (r & 7))) * 16;
  }
#pragma unroll
  for (int j = 0; j < 4; ++j) {
    int r = wn * 64 + j * 16 + lr;
    oB[j] = (r * 8 + (kg ^ (r & 7))) * 16;
  }

  auto stA = [&](int c, int kt, int chunk) {
    int s = chunk * 512 + tid;                    // linear 16B slot
    int prow = s >> 3, ps = s & 7;
    int lc = ps ^ (prow & 7);                     // inverse swizzle on source
    gload_lds16(A + (size_t)(m0 + prow) * K + kt * 64 + lc * 8,
                &sA[c][(size_t)s * 8]);
  };
  auto stB = [&](int c, int kt, int chunk) {
    int s = chunk * 512 + tid;
    int prow = s >> 3, ps = s & 7;
    int lc = ps ^ (prow & 7);
    gload_lds16(BT + (size_t)(n0 + prow) * K + kt * 64 + lc * 8,
                &sB[c][(size_t)s * 8]);
  };

  // prologue: tile 0 into buf 0
#pragma unroll
  for (int ch = 0; ch < 4; ++ch) { stA(0, 0, ch); stB(0, 0, ch); }
  asm volatile("s_waitcnt vmcnt(0)\n\ts_barrier" ::: "memory");

  for (int t = 0; t < KT; ++t) {
    const int c = t & 1;
    const char* bA = (const char*)&sA[c][0];
    const char* bB = (const char*)&sB[c][0];

    bf16x8 af[8], bfr[4];
    // ---- phase 0: k 0..31 ----
#pragma unroll
    for (int i = 0; i < 8; ++i) af[i] = *(const bf16x8*)(bA + oA[i]);
#pragma unroll
    for (int j = 0; j < 4; ++j) bfr[j] = *(const bf16x8*)(bB + oB[j]);

    if (t + 1 < KT) {
#pragma unroll
      for (int ch = 0; ch < 4; ++ch) { stA(c ^ 1, t + 1, ch); stB(c ^ 1, t + 1, ch); }
    }

    __builtin_amdgcn_s_setprio(1);
#pragma unroll
    for (int i = 0; i < 8; ++i)
#pragma unroll
      for (int j = 0; j < 4; ++j)
        acc[i][j] = mfma16(af[i], bfr[j], acc[i][j]);
    __builtin_amdgcn_s_setprio(0);

    // ---- phase 1: k 32..63 ----
#pragma unroll
    for (int i = 0; i < 8; ++i) af[i] = *(const bf16x8*)(bA + (oA[i] ^ 64));
#pragma unroll
    for (int j = 0; j < 4; ++j) bfr[j] = *(const bf16x8*)(bB + (oB[j] ^ 64));

    __builtin_amdgcn_s_setprio(1);
#pragma unroll
    for (int i = 0; i < 8; ++i)
#pragma unroll
      for (int j = 0; j < 4; ++j)
        acc[i][j] = mfma16(af[i], bfr[j], acc[i][j]);
    __builtin_amdgcn_s_setprio(0);

    asm volatile("s_waitcnt vmcnt(0)\n\ts_barrier" ::: "memory");
  }

  // ---- epilogue ----
  const int cb = n0 >> 10;          // uniform per block (256 | 1024)
#pragma unroll
  for (int i = 0; i < 8; ++i) {
#pragma unroll
    for (int jj = 0; jj < 4; ++jj) {
      const int n = n0 + wn * 64 + jj * 16 + lr;
      const int m0r = m0 + wm * 128 + i * 16 + kg * 4;
      if (MODE == 0) {
        const int nn = n & 1023;
        if (cb == 0) {
          const float b_ = bias0[nn];
#pragma unroll
          for (int r = 0; r < 4; ++r)
            Qo[(size_t)(m0r + r) * ADIM + nn] = (bf16)(acc[i][jj][r] + b_);
        } else if (cb == 1) {
          const float b_ = bias1[nn];
#pragma unroll
          for (int r = 0; r < 4; ++r) {
            float v = acc[i][jj][r] + b_;
            Ko[(size_t)(m0r + r) * ADIM + nn] = (bf16)(v > 0.f ? v + 1.f : __expf(v));
          }
        } else {
          const float b_ = bias2[nn];
          const int bb = m0r >> 11, t0c = m0r & 2047;
          bf16x4 pk;
#pragma unroll
          for (int r = 0; r < 4; ++r) pk[r] = (bf16)(acc[i][jj][r] + b_);
          *(bf16x4*)&Vto[((size_t)bb * ADIM + nn) * ASEQ + t0c] = pk;
        }
      } else {
        const float b_ = bias0[n];
#pragma unroll
        for (int r = 0; r < 4; ++r)
          outF[(size_t)(m0r + r) * ADIM + n] = acc[i][jj][r] + b_;
      }
    }
  }
}

// --------- windowed decay attention: one (batch, 64-row q-tile) per WG ---------
__global__ __launch_bounds__(256) void k_attn(
    const bf16* __restrict__ Qg, const bf16* __restrict__ Kg,
    const bf16* __restrict__ Vt, bf16* __restrict__ Rb,
    const float* __restrict__ decay_param)
{
  const int b = blockIdx.y;
  const int T0 = blockIdx.x * 64;
  const int tid = threadIdx.x;
  const int l = tid & 63, w = tid >> 6;
  const int lr = l & 15, lk = (l >> 4) * 8;

  const float dp = decay_param[0];
  const float decay = 1.f / (1.f + __expf(-dp));
  const float l2d = __log2f(decay);

  __shared__ alignas(16) bf16 lQ[2][64 * 32];
  __shared__ alignas(16) bf16 lK[2][128 * 32];
  __shared__ alignas(16) bf16 lV[2][128 * 32];
  __shared__ alignas(16) bf16 lP[64 * 136];

  const bf16* Qb = Qg + (size_t)(b * ASEQ + T0) * ADIM;

  auto stageQK = [&](int buf, int k0) {
    {
      const bf16* g = Qb + (size_t)(w * 16 + (l >> 2)) * ADIM + k0 + (l & 3) * 8;
      gload_lds16(g, &lQ[buf][w * 16 * 32]);
    }
#pragma unroll
    for (int cc = 0; cc < 2; ++cc) {
      int c = 2 * w + cc;
      int sg = T0 - 64 + c * 16 + (l >> 2);
      if (sg < 0) sg = 0;
      const bf16* g = Kg + (size_t)(b * ASEQ + sg) * ADIM + k0 + (l & 3) * 8;
      gload_lds16(g, &lK[buf][c * 16 * 32]);
    }
  };

  f32x4 sc[4][2] = {};
  stageQK(0, 0);
  __syncthreads();
  for (int kt = 0; kt < 32; ++kt) {
    int cur = kt & 1;
    if (kt + 1 < 32) stageQK(cur ^ 1, (kt + 1) * 32);
    bf16x8 af[4], bfr[2];
#pragma unroll
    for (int i = 0; i < 4; ++i)
      af[i] = *(const bf16x8*)&lQ[cur][(i * 16 + lr) * 32 + lk];
#pragma unroll
    for (int j = 0; j < 2; ++j)
      bfr[j] = *(const bf16x8*)&lK[cur][(w * 32 + j * 16 + lr) * 32 + lk];
#pragma unroll
    for (int i = 0; i < 4; ++i)
#pragma unroll
      for (int j = 0; j < 2; ++j)
        sc[i][j] = mfma16(af[i], bfr[j], sc[i][j]);
    __syncthreads();
  }

  const int er = (l >> 4) * 4, ec = l & 15;
#pragma unroll
  for (int i = 0; i < 4; ++i)
#pragma unroll
    for (int j = 0; j < 2; ++j)
#pragma unroll
      for (int r = 0; r < 4; ++r) {
        int tl = i * 16 + er + r;
        int sl = w * 32 + j * 16 + ec;
        int sg = T0 - 64 + sl;
        int delta = (T0 + tl) - 1 - sg;
        float wgt = (delta >= 0 && delta < 64 && sg >= 0)
                        ? exp2f((float)delta * l2d) : 0.f;
        lP[tl * 136 + sl] = (bf16)(sc[i][j][r] * wgt);
      }

  auto stageV = [&](int buf, int g) {
    int nc = g >> 2, ks = g & 3;
#pragma unroll
    for (int cc = 0; cc < 2; ++cc) {
      int c = 2 * w + cc;
      int drow = nc * 128 + c * 16 + (l >> 2);
      int scol = T0 - 64 + ks * 32 + (l & 3) * 8;
      if (scol < 0) scol = 0;
      const bf16* gv = Vt + ((size_t)b * ADIM + drow) * ASEQ + scol;
      gload_lds16(gv, &lV[buf][c * 16 * 32]);
    }
  };

  f32x4 o[4][2] = {};
  stageV(0, 0);
  __syncthreads();

  for (int g = 0; g < 32; ++g) {
    int cur = g & 1;
    if (g + 1 < 32) stageV(cur ^ 1, g + 1);
    int nc = g >> 2, ks = g & 3;
    bf16x8 af[4], bfr[2];
#pragma unroll
    for (int i = 0; i < 4; ++i)
      af[i] = *(const bf16x8*)&lP[(i * 16 + lr) * 136 + ks * 32 + lk];
#pragma unroll
    for (int j = 0; j < 2; ++j)
      bfr[j] = *(const bf16x8*)&lV[cur][(w * 32 + j * 16 + lr) * 32 + lk];
#pragma unroll
    for (int i = 0; i < 4; ++i)
#pragma unroll
      for (int j = 0; j < 2; ++j)
        o[i][j] = mfma16(af[i], bfr[j], o[i][j]);
    if (ks == 3) {
#pragma unroll
      for (int i = 0; i < 4; ++i)
#pragma unroll
        for (int j = 0; j < 2; ++j) {
#pragma unroll
          for (int r = 0; r < 4; ++r) {
            int tl = i * 16 + er + r;
            int dl = nc * 128 + w * 32 + j * 16 + ec;
            Rb[(size_t)(b * ASEQ + T0 + tl) * ADIM + dl] = (bf16)o[i][j][r];
          }
#pragma unroll
          for (int r = 0; r < 4; ++r) o[i][j][r] = 0.f;
        }
    }
    __syncthreads();
  }
}

extern "C" void kernel_launch(void* const* d_in, const int* in_sizes, int n_in,
                              void* d_out, int out_size, void* d_ws, size_t ws_size,
                              hipStream_t stream) {
  const float* x  = (const float*)d_in[0];
  const float* Wq = (const float*)d_in[1];
  const float* bq = (const float*)d_in[2];
  const float* Wk = (const float*)d_in[3];
  const float* bk = (const float*)d_in[4];
  const float* Wv = (const float*)d_in[5];
  const float* bv = (const float*)d_in[6];
  const float* Wo = (const float*)d_in[7];
  const float* bo = (const float*)d_in[8];
  const float* dp = (const float*)d_in[9];
  float* out = (float*)d_out;

  char* ws = (char*)d_ws;
  bf16* Xb  = (bf16*)(ws + ((size_t)0 << 20));    // [16384][1024]
  bf16* Qb  = (bf16*)(ws + ((size_t)32 << 20));
  bf16* Kb  = (bf16*)(ws + ((size_t)64 << 20));
  bf16* Vtb = (bf16*)(ws + ((size_t)96 << 20));   // [8][1024][2048]
  bf16* Rbb = (bf16*)(ws + ((size_t)128 << 20));
  bf16* WcT = (bf16*)(ws + ((size_t)160 << 20));  // [3072][1024]
  bf16* WoT = (bf16*)(ws + ((size_t)166 << 20));  // [1024][1024]

  const int M = ABATCH * ASEQ;  // 16384

  k_cast_x<<<2048, 256, 0, stream>>>(x, Xb, (M * ADIM) / 4);
  k_prep_w_t<<<1024, 256, 0, stream>>>(Wq, Wk, Wv, Wo, WcT, WoT);
  k_gemm64<0><<<768, 512, 0, stream>>>(
      Xb, WcT, bq, bk, bv, Qb, Kb, Vtb, nullptr, 12);
  k_attn<<<dim3(32, 8), 256, 0, stream>>>(Qb, Kb, Vtb, Rbb, dp);
  k_gemm64<1><<<256, 512, 0, stream>>>(
      Rbb, WoT, bo, nullptr, nullptr, nullptr, nullptr, nullptr, out, 4);
}